// Round 12
// baseline (9405.273 us; speedup 1.0000x reference)
//
#include <hip/hip_runtime.h>

// rnn_phy R13 = R10 (8.72ms best, verified) + ONE change: k_attn at 512 threads with
// red2 aliased onto Ks (dead after QK phase) -> 59.6KB LDS, keeps 2 blocks/CU.
// k_tail dropped (R12 isolated it as +0.2ms); ln2->qkv fusion dropped (R11: x7 PART re-read).
// Everything else byte-identical to R10.

#define Nn 512
#define Dd 130
#define DP 132
#define Hh 128
#define Ee 64
#define FFf 2048
#define KG 192
#define TS 68

typedef float v4 __attribute__((ext_vector_type(4)));
typedef float v2 __attribute__((ext_vector_type(2)));

struct Args {
  const float *Tracks, *W_emb, *b_emb, *W_ih, *W_hh, *b_ih, *b_hh;
  const float *qkv_w, *qkv_b, *out_w, *out_b, *ff1_w, *ff1_b, *ff2_w, *ff2_b;
  const float *ln1_s, *ln1_b, *ln2_s, *ln2_b;
  const float *W_sp, *b_sp, *W_p1, *b_p1, *W_p2, *b_p2, *W_pl, *b_pl;
  float *X, *T, *Q, *Kb, *V, *O, *Sh, *C, *X1, *X2, *Y, *PART, *outp;
};

__device__ __forceinline__ float sigm(float x){ return 1.f/(1.f+__expf(-x)); }

// LN reduce over a [64][132] LDS buffer (512 thr = 64 rows x 8 lanes)
#define LN_REDUCE(SCR) \
  { int row_=tid>>3, l8=tid&7; float s1=0.f, s2=0.f; \
    for (int k=0;k<17;k++){ int c=l8+8*k; if(c<Dd){ float v=(SCR)[row_*132+c]; s1+=v; s2+=v*v; } } \
    red1[row_*9+l8]=s1; red2_[row_*9+l8]=s2; } \
  __syncthreads(); \
  if (tid<64){ float s1=0.f,s2=0.f; \
    for (int k=0;k<8;k++){ s1+=red1[tid*9+k]; s2+=red2_[tid*9+k]; } \
    float m=s1/130.f; mu[tid]=m; inv[tid]=rsqrtf(s2/130.f-m*m+1e-5f); } \
  __syncthreads();

// 2x4 register-tile GEMM core over k-major xs/ws (512 threads, 64x64 out)
#define GEMM64(KK) \
  float acc[2][4] = {}; \
  { const float* xp = xs + 2*ig; \
    const float* wp = ws + 4*cg; \
    _Pragma("unroll 4") \
    for (int j=0;j<(KK);j++){ \
      v2 xv = *(const v2*)(xp + j*TS); \
      v4 wv = *(const v4*)(wp + j*TS); \
      _Pragma("unroll") \
      for (int aa=0;aa<2;aa++) \
        _Pragma("unroll") \
        for (int bb=0;bb<4;bb++) acc[aa][bb] += xv[aa]*wv[bb]; \
    } }

// ---------------- proj (+fused ln2 layer2): Sh = ln2(X+f2b+PART) @ W_sp^T + b_sp. grid 16 --------
__global__ __launch_bounds__(512) void k_proj(Args a){
  int rg = blockIdx.x & 7, cs = blockIdx.x >> 3;
  int r0 = rg*64, c0 = cs*64;
  __shared__ alignas(16) float xs[Dd*TS];
  __shared__ alignas(16) float ws[Dd*TS];
  __shared__ float row[64*132];
  __shared__ float red1[64*9], red2_[64*9], mu[64], inv[64];
  int tid = threadIdx.x, cg = tid & 15, ig = tid >> 4;
  const float* f2b = a.ff2_b + 2*Dd;
  const float* lns = a.ln2_s + 2*Dd;
  const float* lnb = a.ln2_b + 2*Dd;
  for (int idx=tid; idx<64*Dd; idx+=512){ int c=idx/Dd, j=idx-c*Dd; ws[j*TS+c] = a.W_sp[(c0+c)*Dd+j]; }
  for (int idx=tid; idx<64*Dd; idx+=512){ int i=idx/Dd, j=idx-i*Dd;
    float sum = a.X[(r0+i)*DP+j] + f2b[j];
    for (int ksl=0;ksl<16;ksl++) sum += a.PART[(ksl*Nn + r0+i)*DP + j];
    row[i*132+j] = sum; }
  __syncthreads();
  LN_REDUCE(row)
  for (int idx=tid; idx<64*Dd; idx+=512){ int i=idx/Dd, j=idx-i*Dd;
    xs[j*TS+i] = (row[i*132+j]-mu[i])*inv[i]*lns[j] + lnb[j]; }
  __syncthreads();
  GEMM64(Dd)
  #pragma unroll
  for (int aa=0;aa<2;aa++){
    int r = r0 + 2*ig + aa, c = c0 + 4*cg;
    v4 o;
    #pragma unroll
    for (int bb=0;bb<4;bb++) o[bb] = acc[aa][bb] + a.b_sp[c+bb];
    *(v4*)&a.Sh[r*Hh+c] = o;
  }
}

// ---------------- out = relu(in@W^T+b)+in (512x128, K=128), grid 16 ----------------
__global__ __launch_bounds__(512) void k_mlp(Args a, const float* inp, const float* W, const float* b, float* outp){
  int rg = blockIdx.x & 7, cs = blockIdx.x >> 3;
  int r0 = rg*64, c0 = cs*64;
  __shared__ alignas(16) float xs[Hh*TS];
  __shared__ alignas(16) float ws[Hh*TS];
  int tid = threadIdx.x, cg = tid & 15, ig = tid >> 4;
  for (int idx=tid; idx<64*Hh; idx+=512){ int i=idx>>7, j=idx&127; xs[j*TS+i] = inp[(r0+i)*Hh+j]; }
  for (int idx=tid; idx<64*Hh; idx+=512){ int c=idx>>7, j=idx&127; ws[j*TS+c] = W[(c0+c)*Hh+j]; }
  __syncthreads();
  GEMM64(Hh)
  #pragma unroll
  for (int aa=0;aa<2;aa++){
    int r = r0 + 2*ig + aa, c = c0 + 4*cg;
    v4 ri = *(const v4*)&inp[r*Hh+c];
    v4 o;
    #pragma unroll
    for (int bb=0;bb<4;bb++) o[bb] = fmaxf(acc[aa][bb]+b[c+bb],0.f) + ri[bb];
    *(v4*)&outp[r*Hh+c] = o;
  }
}

// ---------------- pred head. grid 64 (8 rows/blk), 256 thr ----------------
__global__ __launch_bounds__(256) void k_pout(Args a, int p){
  int r0 = blockIdx.x*8;
  __shared__ float red[16*17];
  int tid = threadIdx.x;
  int o = tid & 15, kq = tid >> 4;
  int ii = o>>1, jj = o&1, r = r0+ii;
  float s = 0.f;
  for (int v=kq*8; v<kq*8+8; v++) s += a.X2[r*Hh+v]*a.W_pl[jj*Hh+v];
  red[o*17+kq] = s;
  __syncthreads();
  if (tid < 16){
    int oo=tid, i2=oo>>1, j=oo&1, rr=r0+i2;
    float av = a.b_pl[j];
    for (int k=0;k<16;k++) av += red[oo*17+k];
    float cf0, cf2;
    if (p==0){ cf0 = a.Tracks[(rr*20+19)*5+1+j]; cf2 = a.Tracks[(rr*20+19)*5+3+j]; }
    else     { cf0 = a.outp[rr*40+(p-1)*4+j];    cf2 = a.outp[rr*40+(p-1)*4+2+j]; }
    float vv = av*0.1f + cf2;
    float pn = av*0.005f + vv*0.1f + cf0;
    a.outp[rr*40+p*4+j]   = pn;
    a.outp[rr*40+p*4+2+j] = vv;
  }
}

// ---------------- emb + LSTM gates. grid 64 = 8rg x 8us, 512 thr ----------------
__global__ __launch_bounds__(512) void k_gates(Args a, int xin_mode, int tstep, int p, int sh_zero){
  int rg = blockIdx.x & 7, us = blockIdx.x >> 3;
  int r0 = rg*64, u0 = us*16;
  __shared__ alignas(16) float xs[KG*TS];
  __shared__ alignas(16) float ws[KG*TS];
  __shared__ float xin[64*4];
  int tid = threadIdx.x, cg = tid & 15, ig = tid >> 4;
  for (int idx=tid; idx<64*4; idx+=512){ int i=idx>>2, j=idx&3; int r=r0+i;
    xin[i*4+j] = (xin_mode==0) ? a.Tracks[(r*20+tstep)*5+1+j] : a.outp[r*40+p*4+j]; }
  for (int idx=tid; idx<64*Hh; idx+=512){ int i=idx>>7, v=idx&127;
    xs[(Ee+v)*TS+i] = sh_zero ? 0.f : a.Sh[(r0+i)*Hh+v]; }
  for (int idx=tid; idx<64*KG; idx+=512){ int row=idx/KG, j=idx-row*KG;
    int u=row>>2, g=row&3; int wrow = g*Hh + u0 + u;
    ws[j*TS+row] = (j<Ee) ? a.W_ih[wrow*Ee+j] : a.W_hh[wrow*Hh+(j-Ee)]; }
  __syncthreads();
  for (int idx=tid; idx<64*Ee; idx+=512){ int e=idx>>6, i=idx&63;
    float s = a.b_emb[e];
    #pragma unroll
    for (int j=0;j<4;j++) s += xin[i*4+j]*a.W_emb[e*4+j];
    xs[e*TS+i] = s; }
  __syncthreads();
  GEMM64(KG)
  int u = u0 + cg;
  #pragma unroll
  for (int rr=0;rr<2;rr++){
    int r = r0 + 2*ig + rr;
    float gi = acc[rr][0] + a.b_ih[u]      + a.b_hh[u];
    float gf = acc[rr][1] + a.b_ih[Hh+u]   + a.b_hh[Hh+u];
    float gg = acc[rr][2] + a.b_ih[2*Hh+u] + a.b_hh[2*Hh+u];
    float go = acc[rr][3] + a.b_ih[3*Hh+u] + a.b_hh[3*Hh+u];
    float cp = sh_zero ? 0.f : a.C[r*Hh+u];
    float c2 = sigm(gf)*cp + sigm(gi)*tanhf(gg);
    a.C[r*Hh+u] = c2;
    a.X[r*DP+u] = sigm(go)*tanhf(c2);
  }
  if (us==0 && tid<128){ int i=tid>>1, jj=tid&1;
    a.X[(r0+i)*DP + Hh + jj] = xin[i*4+jj]; }
}

// ---------------- QKV: 512x390, K=130. grid 56 = 8rg x 7cs, 512 thr ----------------
__global__ __launch_bounds__(512) void k_qkv(Args a, int layer){
  int rg = blockIdx.x & 7, cs = blockIdx.x >> 3;
  int r0 = rg*64, c0 = cs*64;
  __shared__ alignas(16) float xs[Dd*TS];
  __shared__ alignas(16) float ws[Dd*TS];
  const float* qw = a.qkv_w + layer*390*Dd;
  const float* qb = a.qkv_b + layer*390;
  int tid = threadIdx.x, cg = tid & 15, ig = tid >> 4;
  for (int idx=tid; idx<64*Dd; idx+=512){ int i=idx/Dd, j=idx-i*Dd; xs[j*TS+i] = a.X[(r0+i)*DP+j]; }
  for (int idx=tid; idx<64*Dd; idx+=512){ int c=idx/Dd, j=idx-c*Dd; int gc=c0+c;
    ws[j*TS+c] = (gc<390) ? qw[gc*Dd+j] : 0.f; }
  __syncthreads();
  GEMM64(Dd)
  #pragma unroll
  for (int aa=0;aa<2;aa++){
    int r = r0 + 2*ig + aa;
    #pragma unroll
    for (int bb=0;bb<4;bb++){
      int c = c0 + 4*cg + bb;
      if (c < 390){
        float v = acc[aa][bb] + qb[c];
        if (c < Dd)        a.Q [r*DP + c]        = v;
        else if (c < 2*Dd) a.Kb[r*DP + (c-Dd)]   = v;
        else               a.V [r*DP + (c-2*Dd)] = v;
      }
    }
  }
}

// ---------------- attention, register-P, 512 thr, red2 aliased on Ks. grid 320 -------------------
__global__ __launch_bounds__(512) void k_attn(Args a){
  int rg = blockIdx.x & 31, head = blockIdx.x >> 5;
  int r0 = rg*16, hc = head*13;
  __shared__ alignas(16) float smem[7168 + 7168 + 528 + 32];
  float* Ks   = smem;           // [512*14]; dead after QK -> red2 aliases here
  float* Vs   = smem + 7168;    // [512*14]
  float* red  = smem + 14336;   // [16*33]
  float* rowm = smem + 14864;   // [16]
  float* rowsi= smem + 14880;   // [16]
  float* red2 = smem;           // [512*13] alias of Ks
  int tid = threadIdx.x;
  const float scale = rsqrtf(13.f);
  for (int idx=tid; idx<512*13; idx+=512){ int m=idx/13, d=idx-13*m; Ks[m*14+d]=a.Kb[m*DP+hc+d]; }
  for (int idx=tid; idx<512*13; idx+=512){ int m=idx/13, d=idx-13*m; Vs[m*14+d]=a.V[m*DP+hc+d]; }
  __syncthreads();
  int ii = tid>>5, mg = tid&31;
  float q[13];
  #pragma unroll
  for (int d=0;d<13;d++) q[d]=a.Q[(r0+ii)*DP+hc+d]*scale;
  float p[16];
  #pragma unroll
  for (int k=0;k<16;k++){ int m=mg+32*k;
    float s=0.f;
    #pragma unroll
    for (int d=0;d<13;d++) s += q[d]*Ks[m*14+d];
    p[k]=s; }
  { float mx=-1e30f;
    #pragma unroll
    for (int k=0;k<16;k++) mx=fmaxf(mx,p[k]);
    red[ii*33+mg]=mx; }
  __syncthreads();
  if (tid<16){ float mx=-1e30f; for(int k=0;k<32;k++) mx=fmaxf(mx,red[tid*33+k]); rowm[tid]=mx; }
  __syncthreads();
  { float mx=rowm[ii]; float s=0.f;
    #pragma unroll
    for (int k=0;k<16;k++){ float e=__expf(p[k]-mx); p[k]=e; s+=e; }
    red[ii*33+mg]=s; }
  __syncthreads();
  if (tid<16){ float s=0.f; for(int k=0;k<32;k++) s+=red[tid*33+k]; rowsi[tid]=1.f/s; }
  float po[13];
  #pragma unroll
  for (int d=0;d<13;d++) po[d]=0.f;
  #pragma unroll
  for (int k=0;k<16;k++){ int m=mg+32*k;
    float pv = p[k];
    #pragma unroll
    for (int d=0;d<13;d++) po[d] += pv*Vs[m*14+d];
  }
  __syncthreads();   // all QK reads of Ks long done; safe to overwrite via red2
  #pragma unroll
  for (int d=0;d<13;d++) red2[tid*13+d]=po[d];
  __syncthreads();
  if (tid<208){ int i2=tid/13, d=tid-13*i2;
    float acc=0.f;
    for (int l=0;l<32;l++) acc += red2[(i2*32+l)*13+d];
    a.O[(r0+i2)*DP+hc+d]=acc*rowsi[i2]; }
}

// ---------------- attn out-proj + residual: T = O@ow^T + ob + X. grid 24 = 8rg x 3cs, 512 thr -----
__global__ __launch_bounds__(512) void k_oproj(Args a, int layer){
  int rg = blockIdx.x & 7, cs = blockIdx.x >> 3;
  int r0 = rg*64, c0 = cs*64;
  __shared__ alignas(16) float xs[Dd*TS];
  __shared__ alignas(16) float ws[Dd*TS];
  const float* ow = a.out_w + layer*Dd*Dd;
  const float* ob = a.out_b + layer*Dd;
  int tid = threadIdx.x, cg = tid & 15, ig = tid >> 4;
  for (int idx=tid; idx<64*Dd; idx+=512){ int i=idx/Dd, j=idx-i*Dd; xs[j*TS+i]=a.O[(r0+i)*DP+j]; }
  for (int idx=tid; idx<64*Dd; idx+=512){ int c=idx/Dd, j=idx-c*Dd; int gc=c0+c;
    ws[j*TS+c] = (gc<Dd) ? ow[gc*Dd+j] : 0.f; }
  __syncthreads();
  GEMM64(Dd)
  #pragma unroll
  for (int aa=0;aa<2;aa++){
    int r = r0 + 2*ig + aa;
    #pragma unroll
    for (int bb=0;bb<4;bb++){
      int c = c0 + 4*cg + bb;
      if (c < Dd) a.T[r*DP+c] = acc[aa][bb] + ob[c] + a.X[r*DP+c];
    }
  }
}

// ---------------- layernorm mode1: X = ln(X + ff2_b + sum of 16 PART slices). grid 64 ------------
__global__ __launch_bounds__(256) void k_ln(Args a, const float* s, const float* b, int layer){
  int r0 = blockIdx.x*8;
  __shared__ float row[8*132];
  __shared__ float red1[8*33], red2[8*33];
  __shared__ float mu[8], inv[8];
  int tid = threadIdx.x, i = tid>>5, l = tid&31;
  const float* f2b = a.ff2_b + layer*Dd;
  for (int idx=tid; idx<8*Dd; idx+=256){ int ii=idx/Dd, c=idx-ii*Dd;
    float sum = a.X[(r0+ii)*DP+c] + f2b[c];
    for (int ksl=0;ksl<16;ksl++) sum += a.PART[(ksl*Nn + r0+ii)*DP + c];
    row[ii*132+c]=sum; }
  __syncthreads();
  { float s1=0.f, s2=0.f;
    for (int k=0;k<5;k++){ int c=l+32*k; if(c<Dd){ float v=row[i*132+c]; s1+=v; s2+=v*v; } }
    red1[i*33+l]=s1; red2[i*33+l]=s2; }
  __syncthreads();
  if (tid<8){ float s1=0.f,s2=0.f; for(int k=0;k<32;k++){ s1+=red1[tid*33+k]; s2+=red2[tid*33+k]; }
    float m=s1/130.f; mu[tid]=m; inv[tid]=rsqrtf(s2/130.f - m*m + 1e-5f); }
  __syncthreads();
  for (int idx=tid; idx<8*Dd; idx+=256){ int ii=idx/Dd, c=idx-ii*Dd;
    a.X[(r0+ii)*DP+c] = (row[ii*132+c]-mu[ii])*inv[ii]*s[c] + b[c]; }
}

// ---------------- FF1 (+fused ln1, global-stat): Y = relu(ln1(T)@W1^T + b1). grid 256, 512 thr ----
__global__ __launch_bounds__(512) void k_ff1(Args a, int layer){
  int rg = blockIdx.x & 7, cs = blockIdx.x >> 3;
  int r0 = rg*64, c0 = cs*64;
  __shared__ alignas(16) float xs[Dd*TS];
  __shared__ alignas(16) float ws[Dd*TS];
  __shared__ float red1[64*9], red2_[64*9], mu[64], inv[64];
  const float* w1 = a.ff1_w + layer*FFf*Dd;
  const float* b1 = a.ff1_b + layer*FFf;
  const float* lns = a.ln1_s + layer*Dd;
  const float* lnb = a.ln1_b + layer*Dd;
  int tid = threadIdx.x, cg = tid & 15, ig = tid >> 4;
  for (int idx=tid; idx<64*Dd; idx+=512){ int c=idx/Dd, j=idx-c*Dd; ws[j*TS+c]=w1[(c0+c)*Dd+j]; }
  { int row_=tid>>3, l8=tid&7; float s1=0.f, s2=0.f;
    const float* tr = a.T + (r0+row_)*DP;
    for (int k=0;k<17;k++){ int c=l8+8*k; if(c<Dd){ float v=tr[c]; s1+=v; s2+=v*v; } }
    red1[row_*9+l8]=s1; red2_[row_*9+l8]=s2; }
  __syncthreads();
  if (tid<64){ float s1=0.f,s2=0.f;
    for (int k=0;k<8;k++){ s1+=red1[tid*9+k]; s2+=red2_[tid*9+k]; }
    float m=s1/130.f; mu[tid]=m; inv[tid]=rsqrtf(s2/130.f-m*m+1e-5f); }
  __syncthreads();
  for (int idx=tid; idx<64*Dd; idx+=512){ int i=idx/Dd, j=idx-i*Dd;
    float v = (a.T[(r0+i)*DP+j]-mu[i])*inv[i]*lns[j] + lnb[j];
    xs[j*TS+i] = v;
    if (cs==0) a.X[(r0+i)*DP+j] = v; }
  __syncthreads();
  GEMM64(Dd)
  #pragma unroll
  for (int aa=0;aa<2;aa++){
    int r = r0 + 2*ig + aa, c = c0 + 4*cg;
    v4 o;
    #pragma unroll
    for (int bb=0;bb<4;bb++) o[bb] = fmaxf(acc[aa][bb]+b1[c+bb],0.f);
    *(v4*)&a.Y[r*FFf+c] = o;
  }
}

// ---------------- FF2 partials: PART[ks] = Y[:,kslice]@W2[:,kslice]^T. grid 384, 512 thr ----------
__global__ __launch_bounds__(512) void k_ff2(Args a, int layer){
  int b = blockIdx.x;
  int rg = b & 7; int t = b >> 3; int ks = t/3; int cs = t - ks*3;
  int r0 = rg*64, c0 = cs*64, k0 = ks*128;
  __shared__ alignas(16) float xs[128*TS];
  __shared__ alignas(16) float ws[128*TS];
  const float* w2 = a.ff2_w + layer*Dd*FFf;
  int tid = threadIdx.x, cg = tid & 15, ig = tid >> 4;
  for (int idx=tid; idx<64*128; idx+=512){ int i=idx>>7, j=idx&127; xs[j*TS+i]=a.Y[(r0+i)*FFf+k0+j]; }
  for (int idx=tid; idx<64*128; idx+=512){ int c=idx>>7, j=idx&127; int gc=c0+c;
    ws[j*TS+c] = (gc<Dd) ? w2[gc*FFf+k0+j] : 0.f; }
  __syncthreads();
  GEMM64(128)
  #pragma unroll
  for (int aa=0;aa<2;aa++){
    int r = r0 + 2*ig + aa;
    #pragma unroll
    for (int bb=0;bb<4;bb++){
      int c = c0 + 4*cg + bb;
      if (c < Dd) a.PART[(ks*Nn + r)*DP + c] = acc[aa][bb];
    }
  }
}

extern "C" void kernel_launch(void* const* d_in, const int* in_sizes, int n_in,
                              void* d_out, int out_size, void* d_ws, size_t ws_size,
                              hipStream_t stream) {
  (void)in_sizes; (void)n_in; (void)out_size; (void)ws_size;
  Args A;
  const float* const* in = (const float* const*)d_in;
  A.Tracks=in[0]; A.W_emb=in[1]; A.b_emb=in[2]; A.W_ih=in[3]; A.W_hh=in[4]; A.b_ih=in[5]; A.b_hh=in[6];
  A.qkv_w=in[7]; A.qkv_b=in[8]; A.out_w=in[9]; A.out_b=in[10];
  A.ff1_w=in[11]; A.ff1_b=in[12]; A.ff2_w=in[13]; A.ff2_b=in[14];
  A.ln1_s=in[15]; A.ln1_b=in[16]; A.ln2_s=in[17]; A.ln2_b=in[18];
  A.W_sp=in[19]; A.b_sp=in[20]; A.W_p1=in[21]; A.b_p1=in[22]; A.W_p2=in[23]; A.b_p2=in[24];
  A.W_pl=in[25]; A.b_pl=in[26];
  float* ws = (float*)d_ws;
  A.X   = ws;
  A.T   = ws + 67584;
  A.Q   = ws + 135168;
  A.Kb  = ws + 202752;
  A.V   = ws + 270336;
  A.O   = ws + 337920;
  A.Sh  = ws + 405504;
  A.C   = ws + 471040;
  A.X1  = ws + 536576;
  A.X2  = ws + 602112;
  A.Y   = ws + 667648;
  A.PART= ws + 1716224;   // 16 * 512 * 132
  A.outp = (float*)d_out;

  dim3 B5(512), B2(256);
  auto enc = [&](){
    for (int l=0;l<3;l++){
      k_qkv  <<<dim3(56),  B5, 0, stream>>>(A, l);
      k_attn <<<dim3(320), B5, 0, stream>>>(A);
      k_oproj<<<dim3(24),  B5, 0, stream>>>(A, l);
      k_ff1  <<<dim3(256), B5, 0, stream>>>(A, l);   // + fused ln1
      k_ff2  <<<dim3(384), B5, 0, stream>>>(A, l);
      if (l < 2)
        k_ln <<<dim3(64),  B2, 0, stream>>>(A, A.ln2_s+l*Dd, A.ln2_b+l*Dd, l);
    }
  };

  // init step: lstm(emb(Tracks[:,0,1:]), 0, 0) -> encoder
  k_gates<<<dim3(64), B5, 0, stream>>>(A, 0, 0, 0, 1);
  enc();
  // 20 history steps (proj carries fused ln2 of layer 2)
  for (int t=0;t<20;t++){
    k_proj <<<dim3(16), B5, 0, stream>>>(A);
    k_gates<<<dim3(64), B5, 0, stream>>>(A, 0, t, 0, 0);
    enc();
  }
  // 10 prediction steps
  for (int p=0;p<10;p++){
    k_proj<<<dim3(16), B5, 0, stream>>>(A);
    k_mlp <<<dim3(16), B5, 0, stream>>>(A, A.Sh, A.W_p1, A.b_p1, A.X1);
    k_mlp <<<dim3(16), B5, 0, stream>>>(A, A.X1, A.W_p2, A.b_p2, A.X2);
    k_pout<<<dim3(64), B2, 0, stream>>>(A, p);
    if (p < 9){
      k_gates<<<dim3(64), B5, 0, stream>>>(A, 1, 0, p, 0);
      enc();
    }
  }
}

// Round 13
// 8706.638 us; speedup vs baseline: 1.0802x; 1.0802x over previous
//
#include <hip/hip_runtime.h>

// rnn_phy R14 = R10 verbatim — the verified optimum (8.72ms, absmax 0.0).
// Experiment ledger vs R10 (all single-variable, all regressed):
//   R11 ln2->qkv fusion: +0.27ms (PART re-read x7 column blocks)
//   R12 k_tail pred fusion: +0.20ms (grid-8 serial chain slower than 4 launches)
//   R13 512-thr attention: +0.69ms (LDS-port-bound; more waves = more contention)
// Earlier: megakernel (fence=25us/barrier), FATCORE/256-thr GEMMs, LN-in-GEMM-LDS
// variants all regressed. Structure: ~600 launches x ~10-14us dispatch+latency floor;
// compute is ~1.5ms of 8.7ms. R10's wins: register-P attention, occupancy-safe
// ln1->ff1 (global-stat) and ln2(l2)->proj fusions over the R2 512-thr GEMM template.

#define Nn 512
#define Dd 130
#define DP 132
#define Hh 128
#define Ee 64
#define FFf 2048
#define KG 192
#define TS 68

typedef float v4 __attribute__((ext_vector_type(4)));
typedef float v2 __attribute__((ext_vector_type(2)));

struct Args {
  const float *Tracks, *W_emb, *b_emb, *W_ih, *W_hh, *b_ih, *b_hh;
  const float *qkv_w, *qkv_b, *out_w, *out_b, *ff1_w, *ff1_b, *ff2_w, *ff2_b;
  const float *ln1_s, *ln1_b, *ln2_s, *ln2_b;
  const float *W_sp, *b_sp, *W_p1, *b_p1, *W_p2, *b_p2, *W_pl, *b_pl;
  float *X, *T, *Q, *Kb, *V, *O, *Sh, *C, *X1, *X2, *Y, *PART, *outp;
};

__device__ __forceinline__ float sigm(float x){ return 1.f/(1.f+__expf(-x)); }

// LN reduce over row[64*132] LDS buffer (512 thr = 64 rows x 8 lanes)
#define LN_REDUCE(SCR) \
  { int row_=tid>>3, l8=tid&7; float s1=0.f, s2=0.f; \
    for (int k=0;k<17;k++){ int c=l8+8*k; if(c<Dd){ float v=(SCR)[row_*132+c]; s1+=v; s2+=v*v; } } \
    red1[row_*9+l8]=s1; red2_[row_*9+l8]=s2; } \
  __syncthreads(); \
  if (tid<64){ float s1=0.f,s2=0.f; \
    for (int k=0;k<8;k++){ s1+=red1[tid*9+k]; s2+=red2_[tid*9+k]; } \
    float m=s1/130.f; mu[tid]=m; inv[tid]=rsqrtf(s2/130.f-m*m+1e-5f); } \
  __syncthreads();

// ---------------- proj (+fused ln2 layer2): Sh = ln2(X+f2b+PART) @ W_sp^T + b_sp. grid 16 --------
__global__ __launch_bounds__(512) void k_proj(Args a){
  int rg = blockIdx.x & 7, cs = blockIdx.x >> 3;
  int r0 = rg*64, c0 = cs*64;
  __shared__ alignas(16) float xs[Dd*TS];
  __shared__ alignas(16) float ws[Dd*TS];
  __shared__ float row[64*132];
  __shared__ float red1[64*9], red2_[64*9], mu[64], inv[64];
  int tid = threadIdx.x, cg = tid & 15, ig = tid >> 4;
  const float* f2b = a.ff2_b + 2*Dd;
  const float* lns = a.ln2_s + 2*Dd;
  const float* lnb = a.ln2_b + 2*Dd;
  for (int idx=tid; idx<64*Dd; idx+=512){ int c=idx/Dd, j=idx-c*Dd; ws[j*TS+c] = a.W_sp[(c0+c)*Dd+j]; }
  for (int idx=tid; idx<64*Dd; idx+=512){ int i=idx/Dd, j=idx-i*Dd;
    float sum = a.X[(r0+i)*DP+j] + f2b[j];
    for (int ksl=0;ksl<16;ksl++) sum += a.PART[(ksl*Nn + r0+i)*DP + j];
    row[i*132+j] = sum; }
  __syncthreads();
  LN_REDUCE(row)
  for (int idx=tid; idx<64*Dd; idx+=512){ int i=idx/Dd, j=idx-i*Dd;
    xs[j*TS+i] = (row[i*132+j]-mu[i])*inv[i]*lns[j] + lnb[j]; }
  __syncthreads();
  float acc[2][4] = {};
  const float* xp = xs + 2*ig;
  const float* wp = ws + 4*cg;
  #pragma unroll 4
  for (int j=0;j<Dd;j++){
    v2 xv = *(const v2*)(xp + j*TS);
    v4 wv = *(const v4*)(wp + j*TS);
    #pragma unroll
    for (int aa=0;aa<2;aa++)
      #pragma unroll
      for (int bb=0;bb<4;bb++) acc[aa][bb] += xv[aa]*wv[bb];
  }
  #pragma unroll
  for (int aa=0;aa<2;aa++){
    int r = r0 + 2*ig + aa, c = c0 + 4*cg;
    v4 o;
    #pragma unroll
    for (int bb=0;bb<4;bb++) o[bb] = acc[aa][bb] + a.b_sp[c+bb];
    *(v4*)&a.Sh[r*Hh+c] = o;
  }
}

// ---------------- out = relu(in@W^T+b)+in (512x128, K=128), grid 16 ----------------
__global__ __launch_bounds__(512) void k_mlp(Args a, const float* inp, const float* W, const float* b, float* outp){
  int rg = blockIdx.x & 7, cs = blockIdx.x >> 3;
  int r0 = rg*64, c0 = cs*64;
  __shared__ alignas(16) float xs[Hh*TS];
  __shared__ alignas(16) float ws[Hh*TS];
  int tid = threadIdx.x, cg = tid & 15, ig = tid >> 4;
  for (int idx=tid; idx<64*Hh; idx+=512){ int i=idx>>7, j=idx&127; xs[j*TS+i] = inp[(r0+i)*Hh+j]; }
  for (int idx=tid; idx<64*Hh; idx+=512){ int c=idx>>7, j=idx&127; ws[j*TS+c] = W[(c0+c)*Hh+j]; }
  __syncthreads();
  float acc[2][4] = {};
  const float* xp = xs + 2*ig;
  const float* wp = ws + 4*cg;
  #pragma unroll 4
  for (int j=0;j<Hh;j++){
    v2 xv = *(const v2*)(xp + j*TS);
    v4 wv = *(const v4*)(wp + j*TS);
    #pragma unroll
    for (int aa=0;aa<2;aa++)
      #pragma unroll
      for (int bb=0;bb<4;bb++) acc[aa][bb] += xv[aa]*wv[bb];
  }
  #pragma unroll
  for (int aa=0;aa<2;aa++){
    int r = r0 + 2*ig + aa, c = c0 + 4*cg;
    v4 ri = *(const v4*)&inp[r*Hh+c];
    v4 o;
    #pragma unroll
    for (int bb=0;bb<4;bb++) o[bb] = fmaxf(acc[aa][bb]+b[c+bb],0.f) + ri[bb];
    *(v4*)&outp[r*Hh+c] = o;
  }
}

// ---------------- pred head. grid 64 (8 rows/blk), 256 thr ----------------
__global__ __launch_bounds__(256) void k_pout(Args a, int p){
  int r0 = blockIdx.x*8;
  __shared__ float red[16*17];
  int tid = threadIdx.x;
  int o = tid & 15, kq = tid >> 4;
  int ii = o>>1, jj = o&1, r = r0+ii;
  float s = 0.f;
  for (int v=kq*8; v<kq*8+8; v++) s += a.X2[r*Hh+v]*a.W_pl[jj*Hh+v];
  red[o*17+kq] = s;
  __syncthreads();
  if (tid < 16){
    int oo=tid, i2=oo>>1, j=oo&1, rr=r0+i2;
    float av = a.b_pl[j];
    for (int k=0;k<16;k++) av += red[oo*17+k];
    float cf0, cf2;
    if (p==0){ cf0 = a.Tracks[(rr*20+19)*5+1+j]; cf2 = a.Tracks[(rr*20+19)*5+3+j]; }
    else     { cf0 = a.outp[rr*40+(p-1)*4+j];    cf2 = a.outp[rr*40+(p-1)*4+2+j]; }
    float vv = av*0.1f + cf2;
    float pn = av*0.005f + vv*0.1f + cf0;
    a.outp[rr*40+p*4+j]   = pn;
    a.outp[rr*40+p*4+2+j] = vv;
  }
}

// ---------------- emb + LSTM gates. grid 64 = 8rg x 8us, 512 thr ----------------
__global__ __launch_bounds__(512) void k_gates(Args a, int xin_mode, int tstep, int p, int sh_zero){
  int rg = blockIdx.x & 7, us = blockIdx.x >> 3;
  int r0 = rg*64, u0 = us*16;
  __shared__ alignas(16) float xs[KG*TS];
  __shared__ alignas(16) float ws[KG*TS];
  __shared__ float xin[64*4];
  int tid = threadIdx.x, cg = tid & 15, ig = tid >> 4;
  for (int idx=tid; idx<64*4; idx+=512){ int i=idx>>2, j=idx&3; int r=r0+i;
    xin[i*4+j] = (xin_mode==0) ? a.Tracks[(r*20+tstep)*5+1+j] : a.outp[r*40+p*4+j]; }
  for (int idx=tid; idx<64*Hh; idx+=512){ int i=idx>>7, v=idx&127;
    xs[(Ee+v)*TS+i] = sh_zero ? 0.f : a.Sh[(r0+i)*Hh+v]; }
  for (int idx=tid; idx<64*KG; idx+=512){ int row=idx/KG, j=idx-row*KG;
    int u=row>>2, g=row&3; int wrow = g*Hh + u0 + u;
    ws[j*TS+row] = (j<Ee) ? a.W_ih[wrow*Ee+j] : a.W_hh[wrow*Hh+(j-Ee)]; }
  __syncthreads();
  for (int idx=tid; idx<64*Ee; idx+=512){ int e=idx>>6, i=idx&63;
    float s = a.b_emb[e];
    #pragma unroll
    for (int j=0;j<4;j++) s += xin[i*4+j]*a.W_emb[e*4+j];
    xs[e*TS+i] = s; }
  __syncthreads();
  float acc[2][4] = {};
  const float* xp = xs + 2*ig;
  const float* wp = ws + 4*cg;
  #pragma unroll 4
  for (int j=0;j<KG;j++){
    v2 xv = *(const v2*)(xp + j*TS);
    v4 wv = *(const v4*)(wp + j*TS);
    #pragma unroll
    for (int aa=0;aa<2;aa++)
      #pragma unroll
      for (int bb=0;bb<4;bb++) acc[aa][bb] += xv[aa]*wv[bb];
  }
  int u = u0 + cg;
  #pragma unroll
  for (int rr=0;rr<2;rr++){
    int r = r0 + 2*ig + rr;
    float gi = acc[rr][0] + a.b_ih[u]      + a.b_hh[u];
    float gf = acc[rr][1] + a.b_ih[Hh+u]   + a.b_hh[Hh+u];
    float gg = acc[rr][2] + a.b_ih[2*Hh+u] + a.b_hh[2*Hh+u];
    float go = acc[rr][3] + a.b_ih[3*Hh+u] + a.b_hh[3*Hh+u];
    float cp = sh_zero ? 0.f : a.C[r*Hh+u];
    float c2 = sigm(gf)*cp + sigm(gi)*tanhf(gg);
    a.C[r*Hh+u] = c2;
    a.X[r*DP+u] = sigm(go)*tanhf(c2);
  }
  if (us==0 && tid<128){ int i=tid>>1, jj=tid&1;
    a.X[(r0+i)*DP + Hh + jj] = xin[i*4+jj]; }
}

// ---------------- QKV: 512x390, K=130. grid 56 = 8rg x 7cs, 512 thr ----------------
__global__ __launch_bounds__(512) void k_qkv(Args a, int layer){
  int rg = blockIdx.x & 7, cs = blockIdx.x >> 3;
  int r0 = rg*64, c0 = cs*64;
  __shared__ alignas(16) float xs[Dd*TS];
  __shared__ alignas(16) float ws[Dd*TS];
  const float* qw = a.qkv_w + layer*390*Dd;
  const float* qb = a.qkv_b + layer*390;
  int tid = threadIdx.x, cg = tid & 15, ig = tid >> 4;
  for (int idx=tid; idx<64*Dd; idx+=512){ int i=idx/Dd, j=idx-i*Dd; xs[j*TS+i] = a.X[(r0+i)*DP+j]; }
  for (int idx=tid; idx<64*Dd; idx+=512){ int c=idx/Dd, j=idx-c*Dd; int gc=c0+c;
    ws[j*TS+c] = (gc<390) ? qw[gc*Dd+j] : 0.f; }
  __syncthreads();
  float acc[2][4] = {};
  const float* xp = xs + 2*ig;
  const float* wp = ws + 4*cg;
  #pragma unroll 4
  for (int j=0;j<Dd;j++){
    v2 xv = *(const v2*)(xp + j*TS);
    v4 wv = *(const v4*)(wp + j*TS);
    #pragma unroll
    for (int aa=0;aa<2;aa++)
      #pragma unroll
      for (int bb=0;bb<4;bb++) acc[aa][bb] += xv[aa]*wv[bb];
  }
  #pragma unroll
  for (int aa=0;aa<2;aa++){
    int r = r0 + 2*ig + aa;
    #pragma unroll
    for (int bb=0;bb<4;bb++){
      int c = c0 + 4*cg + bb;
      if (c < 390){
        float v = acc[aa][bb] + qb[c];
        if (c < Dd)        a.Q [r*DP + c]        = v;
        else if (c < 2*Dd) a.Kb[r*DP + (c-Dd)]   = v;
        else               a.V [r*DP + (c-2*Dd)] = v;
      }
    }
  }
}

// ---------------- attention, register-P: grid 320 (16 rows x head), 256 thr ----------------
__global__ __launch_bounds__(256) void k_attn(Args a){
  int rg = blockIdx.x & 31, head = blockIdx.x >> 5;
  int r0 = rg*16, hc = head*13;
  __shared__ alignas(16) float Ks[512*14];
  __shared__ alignas(16) float Vs[512*14];
  __shared__ float red[16*17];
  __shared__ float rowm[16], rowsi[16];
  __shared__ float red2[256*13];
  int tid = threadIdx.x;
  const float scale = rsqrtf(13.f);
  for (int idx=tid; idx<512*13; idx+=256){ int m=idx/13, d=idx-13*m; Ks[m*14+d]=a.Kb[m*DP+hc+d]; }
  for (int idx=tid; idx<512*13; idx+=256){ int m=idx/13, d=idx-13*m; Vs[m*14+d]=a.V[m*DP+hc+d]; }
  __syncthreads();
  int ii = tid>>4, mg = tid&15;
  float q[13];
  #pragma unroll
  for (int d=0;d<13;d++) q[d]=a.Q[(r0+ii)*DP+hc+d]*scale;
  float p[32];
  #pragma unroll
  for (int k=0;k<32;k++){ int m=mg+16*k;
    float s=0.f;
    #pragma unroll
    for (int d=0;d<13;d++) s += q[d]*Ks[m*14+d];
    p[k]=s; }
  { float mx=-1e30f;
    #pragma unroll
    for (int k=0;k<32;k++) mx=fmaxf(mx,p[k]);
    red[ii*17+mg]=mx; }
  __syncthreads();
  if (tid<16){ float mx=-1e30f; for(int k=0;k<16;k++) mx=fmaxf(mx,red[tid*17+k]); rowm[tid]=mx; }
  __syncthreads();
  { float mx=rowm[ii]; float s=0.f;
    #pragma unroll
    for (int k=0;k<32;k++){ float e=__expf(p[k]-mx); p[k]=e; s+=e; }
    red[ii*17+mg]=s; }
  __syncthreads();
  if (tid<16){ float s=0.f; for(int k=0;k<16;k++) s+=red[tid*17+k]; rowsi[tid]=1.f/s; }
  float po[13];
  #pragma unroll
  for (int d=0;d<13;d++) po[d]=0.f;
  #pragma unroll
  for (int k=0;k<32;k++){ int m=mg+16*k;
    float pv = p[k];
    #pragma unroll
    for (int d=0;d<13;d++) po[d] += pv*Vs[m*14+d];
  }
  #pragma unroll
  for (int d=0;d<13;d++) red2[tid*13+d]=po[d];
  __syncthreads();
  if (tid<208){ int i2=tid/13, d=tid-13*i2;
    float acc=0.f;
    for (int l=0;l<16;l++) acc += red2[(i2*16+l)*13+d];
    a.O[(r0+i2)*DP+hc+d]=acc*rowsi[i2]; }
}

// ---------------- attn out-proj + residual: T = O@ow^T + ob + X. grid 24 = 8rg x 3cs, 512 thr -----
__global__ __launch_bounds__(512) void k_oproj(Args a, int layer){
  int rg = blockIdx.x & 7, cs = blockIdx.x >> 3;
  int r0 = rg*64, c0 = cs*64;
  __shared__ alignas(16) float xs[Dd*TS];
  __shared__ alignas(16) float ws[Dd*TS];
  const float* ow = a.out_w + layer*Dd*Dd;
  const float* ob = a.out_b + layer*Dd;
  int tid = threadIdx.x, cg = tid & 15, ig = tid >> 4;
  for (int idx=tid; idx<64*Dd; idx+=512){ int i=idx/Dd, j=idx-i*Dd; xs[j*TS+i]=a.O[(r0+i)*DP+j]; }
  for (int idx=tid; idx<64*Dd; idx+=512){ int c=idx/Dd, j=idx-c*Dd; int gc=c0+c;
    ws[j*TS+c] = (gc<Dd) ? ow[gc*Dd+j] : 0.f; }
  __syncthreads();
  float acc[2][4] = {};
  const float* xp = xs + 2*ig;
  const float* wp = ws + 4*cg;
  #pragma unroll 4
  for (int j=0;j<Dd;j++){
    v2 xv = *(const v2*)(xp + j*TS);
    v4 wv = *(const v4*)(wp + j*TS);
    #pragma unroll
    for (int aa=0;aa<2;aa++)
      #pragma unroll
      for (int bb=0;bb<4;bb++) acc[aa][bb] += xv[aa]*wv[bb];
  }
  #pragma unroll
  for (int aa=0;aa<2;aa++){
    int r = r0 + 2*ig + aa;
    #pragma unroll
    for (int bb=0;bb<4;bb++){
      int c = c0 + 4*cg + bb;
      if (c < Dd) a.T[r*DP+c] = acc[aa][bb] + ob[c] + a.X[r*DP+c];
    }
  }
}

// ---------------- layernorm mode1: X = ln(X + ff2_b + sum of 16 PART slices). grid 64 ------------
__global__ __launch_bounds__(256) void k_ln(Args a, const float* s, const float* b, int layer){
  int r0 = blockIdx.x*8;
  __shared__ float row[8*132];
  __shared__ float red1[8*33], red2[8*33];
  __shared__ float mu[8], inv[8];
  int tid = threadIdx.x, i = tid>>5, l = tid&31;
  const float* f2b = a.ff2_b + layer*Dd;
  for (int idx=tid; idx<8*Dd; idx+=256){ int ii=idx/Dd, c=idx-ii*Dd;
    float sum = a.X[(r0+ii)*DP+c] + f2b[c];
    for (int ksl=0;ksl<16;ksl++) sum += a.PART[(ksl*Nn + r0+ii)*DP + c];
    row[ii*132+c]=sum; }
  __syncthreads();
  { float s1=0.f, s2=0.f;
    for (int k=0;k<5;k++){ int c=l+32*k; if(c<Dd){ float v=row[i*132+c]; s1+=v; s2+=v*v; } }
    red1[i*33+l]=s1; red2[i*33+l]=s2; }
  __syncthreads();
  if (tid<8){ float s1=0.f,s2=0.f; for(int k=0;k<32;k++){ s1+=red1[tid*33+k]; s2+=red2[tid*33+k]; }
    float m=s1/130.f; mu[tid]=m; inv[tid]=rsqrtf(s2/130.f - m*m + 1e-5f); }
  __syncthreads();
  for (int idx=tid; idx<8*Dd; idx+=256){ int ii=idx/Dd, c=idx-ii*Dd;
    a.X[(r0+ii)*DP+c] = (row[ii*132+c]-mu[ii])*inv[ii]*s[c] + b[c]; }
}

// ---------------- FF1 (+fused ln1, global-stat): Y = relu(ln1(T)@W1^T + b1). grid 256, 512 thr ----
__global__ __launch_bounds__(512) void k_ff1(Args a, int layer){
  int rg = blockIdx.x & 7, cs = blockIdx.x >> 3;
  int r0 = rg*64, c0 = cs*64;
  __shared__ alignas(16) float xs[Dd*TS];
  __shared__ alignas(16) float ws[Dd*TS];
  __shared__ float red1[64*9], red2_[64*9], mu[64], inv[64];
  const float* w1 = a.ff1_w + layer*FFf*Dd;
  const float* b1 = a.ff1_b + layer*FFf;
  const float* lns = a.ln1_s + layer*Dd;
  const float* lnb = a.ln1_b + layer*Dd;
  int tid = threadIdx.x, cg = tid & 15, ig = tid >> 4;
  // weights first (overlaps LN stats)
  for (int idx=tid; idx<64*Dd; idx+=512){ int c=idx/Dd, j=idx-c*Dd; ws[j*TS+c]=w1[(c0+c)*Dd+j]; }
  // LN stats straight from global T (L2-warm, no row LDS buffer -> keeps 2 blocks/CU)
  { int row_=tid>>3, l8=tid&7; float s1=0.f, s2=0.f;
    const float* tr = a.T + (r0+row_)*DP;
    for (int k=0;k<17;k++){ int c=l8+8*k; if(c<Dd){ float v=tr[c]; s1+=v; s2+=v*v; } }
    red1[row_*9+l8]=s1; red2_[row_*9+l8]=s2; }
  __syncthreads();
  if (tid<64){ float s1=0.f,s2=0.f;
    for (int k=0;k<8;k++){ s1+=red1[tid*9+k]; s2+=red2_[tid*9+k]; }
    float m=s1/130.f; mu[tid]=m; inv[tid]=rsqrtf(s2/130.f-m*m+1e-5f); }
  __syncthreads();
  for (int idx=tid; idx<64*Dd; idx+=512){ int i=idx/Dd, j=idx-i*Dd;
    float v = (a.T[(r0+i)*DP+j]-mu[i])*inv[i]*lns[j] + lnb[j];
    xs[j*TS+i] = v;
    if (cs==0) a.X[(r0+i)*DP+j] = v; }
  __syncthreads();
  float acc[2][4] = {};
  const float* xp = xs + 2*ig;
  const float* wp = ws + 4*cg;
  #pragma unroll 4
  for (int j=0;j<Dd;j++){
    v2 xv = *(const v2*)(xp + j*TS);
    v4 wv = *(const v4*)(wp + j*TS);
    #pragma unroll
    for (int aa=0;aa<2;aa++)
      #pragma unroll
      for (int bb=0;bb<4;bb++) acc[aa][bb] += xv[aa]*wv[bb];
  }
  #pragma unroll
  for (int aa=0;aa<2;aa++){
    int r = r0 + 2*ig + aa, c = c0 + 4*cg;
    v4 o;
    #pragma unroll
    for (int bb=0;bb<4;bb++) o[bb] = fmaxf(acc[aa][bb]+b1[c+bb],0.f);
    *(v4*)&a.Y[r*FFf+c] = o;
  }
}

// ---------------- FF2 partials: PART[ks] = Y[:,kslice]@W2[:,kslice]^T. grid 384, 512 thr ----------
__global__ __launch_bounds__(512) void k_ff2(Args a, int layer){
  int b = blockIdx.x;
  int rg = b & 7; int t = b >> 3; int ks = t/3; int cs = t - ks*3;
  int r0 = rg*64, c0 = cs*64, k0 = ks*128;
  __shared__ alignas(16) float xs[128*TS];
  __shared__ alignas(16) float ws[128*TS];
  const float* w2 = a.ff2_w + layer*Dd*FFf;
  int tid = threadIdx.x, cg = tid & 15, ig = tid >> 4;
  for (int idx=tid; idx<64*128; idx+=512){ int i=idx>>7, j=idx&127; xs[j*TS+i]=a.Y[(r0+i)*FFf+k0+j]; }
  for (int idx=tid; idx<64*128; idx+=512){ int c=idx>>7, j=idx&127; int gc=c0+c;
    ws[j*TS+c] = (gc<Dd) ? w2[gc*FFf+k0+j] : 0.f; }
  __syncthreads();
  float acc[2][4] = {};
  const float* xp = xs + 2*ig;
  const float* wp = ws + 4*cg;
  #pragma unroll 4
  for (int j=0;j<128;j++){
    v2 xv = *(const v2*)(xp + j*TS);
    v4 wv = *(const v4*)(wp + j*TS);
    #pragma unroll
    for (int aa=0;aa<2;aa++)
      #pragma unroll
      for (int bb=0;bb<4;bb++) acc[aa][bb] += xv[aa]*wv[bb];
  }
  #pragma unroll
  for (int aa=0;aa<2;aa++){
    int r = r0 + 2*ig + aa;
    #pragma unroll
    for (int bb=0;bb<4;bb++){
      int c = c0 + 4*cg + bb;
      if (c < Dd) a.PART[(ks*Nn + r)*DP + c] = acc[aa][bb];
    }
  }
}

extern "C" void kernel_launch(void* const* d_in, const int* in_sizes, int n_in,
                              void* d_out, int out_size, void* d_ws, size_t ws_size,
                              hipStream_t stream) {
  (void)in_sizes; (void)n_in; (void)out_size; (void)ws_size;
  Args A;
  const float* const* in = (const float* const*)d_in;
  A.Tracks=in[0]; A.W_emb=in[1]; A.b_emb=in[2]; A.W_ih=in[3]; A.W_hh=in[4]; A.b_ih=in[5]; A.b_hh=in[6];
  A.qkv_w=in[7]; A.qkv_b=in[8]; A.out_w=in[9]; A.out_b=in[10];
  A.ff1_w=in[11]; A.ff1_b=in[12]; A.ff2_w=in[13]; A.ff2_b=in[14];
  A.ln1_s=in[15]; A.ln1_b=in[16]; A.ln2_s=in[17]; A.ln2_b=in[18];
  A.W_sp=in[19]; A.b_sp=in[20]; A.W_p1=in[21]; A.b_p1=in[22]; A.W_p2=in[23]; A.b_p2=in[24];
  A.W_pl=in[25]; A.b_pl=in[26];
  float* ws = (float*)d_ws;
  A.X   = ws;
  A.T   = ws + 67584;
  A.Q   = ws + 135168;
  A.Kb  = ws + 202752;
  A.V   = ws + 270336;
  A.O   = ws + 337920;
  A.Sh  = ws + 405504;
  A.C   = ws + 471040;
  A.X1  = ws + 536576;
  A.X2  = ws + 602112;
  A.Y   = ws + 667648;
  A.PART= ws + 1716224;   // 16 * 512 * 132
  A.outp = (float*)d_out;

  dim3 B5(512), B2(256);
  auto enc = [&](){
    for (int l=0;l<3;l++){
      k_qkv  <<<dim3(56),  B5, 0, stream>>>(A, l);
      k_attn <<<dim3(320), B2, 0, stream>>>(A);
      k_oproj<<<dim3(24),  B5, 0, stream>>>(A, l);
      k_ff1  <<<dim3(256), B5, 0, stream>>>(A, l);   // + fused ln1
      k_ff2  <<<dim3(384), B5, 0, stream>>>(A, l);
      if (l < 2)
        k_ln <<<dim3(64),  B2, 0, stream>>>(A, A.ln2_s+l*Dd, A.ln2_b+l*Dd, l);
    }
  };

  // init step: lstm(emb(Tracks[:,0,1:]), 0, 0) -> encoder
  k_gates<<<dim3(64), B5, 0, stream>>>(A, 0, 0, 0, 1);
  enc();
  // 20 history steps (proj carries fused ln2 of layer 2)
  for (int t=0;t<20;t++){
    k_proj <<<dim3(16), B5, 0, stream>>>(A);
    k_gates<<<dim3(64), B5, 0, stream>>>(A, 0, t, 0, 0);
    enc();
  }
  // 10 prediction steps
  for (int p=0;p<10;p++){
    k_proj<<<dim3(16), B5, 0, stream>>>(A);
    k_mlp <<<dim3(16), B5, 0, stream>>>(A, A.Sh, A.W_p1, A.b_p1, A.X1);
    k_mlp <<<dim3(16), B5, 0, stream>>>(A, A.X1, A.W_p2, A.b_p2, A.X2);
    k_pout<<<dim3(64), B2, 0, stream>>>(A, p);
    if (p < 9){
      k_gates<<<dim3(64), B5, 0, stream>>>(A, 1, 0, p, 0);
      enc();
    }
  }
}